// Round 14
// baseline (904.185 us; speedup 1.0000x reference)
//
#include <hip/hip_runtime.h>

// LSTM: VOCAB=50000, EMBED=50, NFEAT=3, T=120, HIDDEN=300, NCLASS=5, BATCH=1024
// R14: L2-local flags. h-data path unchanged (R8-proven). Flags now use the
// SAME L2 mechanism: producer {vmcnt; plain flag-word store}; consumer
// whole-wave {buffer_inv; s_waitcnt; volatile loads; AND} poll. Replay
// staleness handled by per-block flag clear (plain stores, same L2) + one-time
// AGENT-atomic ready[bg] rendezvous (proven pair, amortized). y-projection on
// dedicated blocks (ranks 20-23 per XCD, same L2). NSLOT=8 WAR slack.

#define BATCH 1024
#define TT    120
#define HID   300
#define KX    160
#define KH    320   // 5 slices * 64
#define SL    64
#define HSL   60
#define NCOL  1280  // 5 slices * 256 packed gate columns
#define GH    5
#define GB    32
#define BS    32
#define XST   168   // x_lds row stride in shorts
#define FSTR  32    // flag ints per (t,bg) (128B)
#define NSLOT 8
#define NB    256

typedef __attribute__((ext_vector_type(8))) short bf16x8;
typedef __attribute__((ext_vector_type(4))) float f32x4;

__device__ __forceinline__ unsigned short f2b(float f) {
  union { float f; unsigned u; } v; v.f = f;
  unsigned r = v.u + 0x7fffu + ((v.u >> 16) & 1u);
  return (unsigned short)(r >> 16);
}
__device__ __forceinline__ float sigm(float x) {
  return __builtin_amdgcn_rcpf(1.f + __expf(-x));
}
__device__ __forceinline__ float tanhf_(float x) {
  return 2.f * __builtin_amdgcn_rcpf(1.f + __expf(-2.f * x)) - 1.f;
}
// MFMA with B operand pinned to AGPRs (R13-proven)
__device__ __forceinline__ void mfma_bA(bf16x8 a, const bf16x8& b, f32x4& c) {
  asm("v_mfma_f32_16x16x32_bf16 %0, %1, %2, %0" : "+v"(c) : "v"(a), "a"(b));
}
// whole-wave poll of 20 flag words in local L2 (uniform branch, wave-wide inv)
__device__ __forceinline__ void poll20(const int* fl) {
  int it = 0;
  while (true) {
    asm volatile("buffer_inv\n\ts_waitcnt vmcnt(0)" ::: "memory");
    const volatile int* f = (const volatile int*)fl;
    int a = f[0] & f[1] & f[2] & f[3] & f[4] & f[5] & f[6] & f[7] & f[8] & f[9] &
            f[10] & f[11] & f[12] & f[13] & f[14] & f[15] & f[16] & f[17] & f[18] & f[19];
    if (a == -1) break;
    if (++it > 50000) break;   // bail -> wrong answer (loud), not a hang
  }
}

__global__ void k_reorder_wh(const float* __restrict__ W, unsigned short* __restrict__ Wp) {
  int tid = blockIdx.x * 256 + threadIdx.x;
  if (tid >= KH * NCOL) return;
  int c = tid % NCOL, k = tid / NCOL;
  int js = k >> 6, v0 = k & 63;
  int j = c >> 8, r = c & 255, g = r >> 6, u0 = r & 63;
  float val = 0.f;
  if (v0 < HSL && u0 < HSL) val = W[(js * HSL + v0) * 1200 + g * 300 + j * HSL + u0];
  Wp[((k >> 3) * NCOL + c) * 8 + (k & 7)] = f2b(val);
}

__global__ void k_reorder_wx(const float* __restrict__ W, unsigned short* __restrict__ Wp) {
  int tid = blockIdx.x * 256 + threadIdx.x;
  if (tid >= KX * NCOL) return;
  int c = tid % NCOL, k = tid / NCOL;
  int j = c >> 8, r = c & 255, g = r >> 6, u0 = r & 63;
  float val = 0.f;
  if (k < 150 && u0 < HSL) val = W[k * 1200 + g * 300 + j * HSL + u0];
  Wp[((k >> 3) * NCOL + c) * 8 + (k & 7)] = f2b(val);
}

__global__ void k_reorder_b(const float* __restrict__ b, float* __restrict__ bp) {
  int c = blockIdx.x * 256 + threadIdx.x;
  if (c >= NCOL) return;
  int j = c >> 8, r = c & 255, g = r >> 6, u0 = r & 63;
  bp[c] = (u0 < HSL) ? b[g * 300 + j * HSL + u0] : 0.f;
}

__global__ void k_reorder_u(const float* __restrict__ U, unsigned short* __restrict__ Up) {
  int tid = blockIdx.x * 256 + threadIdx.x;
  if (tid >= KH * 16) return;
  int n = tid % 16, k = tid / 16;
  int js = k >> 6, v0 = k & 63;
  float v = (v0 < HSL && n < 5) ? U[(js * HSL + v0) * 5 + n] : 0.f;
  Up[((k >> 3) * 16 + n) * 8 + (k & 7)] = f2b(v);
}

// AGENT-atomic init for ready/xcd_cnt (visible to AGENT readers across replays)
__global__ void k_init(int* __restrict__ ready, int* __restrict__ xcd_cnt) {
  int i = blockIdx.x * 256 + threadIdx.x;
  if (i < GB * FSTR)
    __hip_atomic_store(ready + i, 0, __ATOMIC_RELAXED, __HIP_MEMORY_SCOPE_AGENT);
  if (i < 8)
    __hip_atomic_store(xcd_cnt + i, 0, __ATOMIC_RELAXED, __HIP_MEMORY_SCOPE_AGENT);
}

__launch_bounds__(256, 1)
__global__ void k_lstm(const int* __restrict__ ids, const float* __restrict__ embed,
                       const unsigned short* __restrict__ Wp,
                       const unsigned short* __restrict__ Wxp,
                       const float* __restrict__ bp,
                       const unsigned short* __restrict__ Up,
                       unsigned short* __restrict__ hbuf,   // [8][1024][320] bf16
                       int* __restrict__ flags,             // [120][32][32] ints
                       int* __restrict__ ready,             // [32] @128B
                       int* __restrict__ xcd_cnt,           // [8]
                       const float* __restrict__ b2,
                       float* __restrict__ out) {
  __shared__ __align__(16) unsigned short x_lds[2][BS * XST];
  __shared__ char lds_pad[61440];   // force 1 block/CU
  __shared__ int role[2];

  const int tid = threadIdx.x;
  if (tid == 0) {
    ((volatile char*)lds_pad)[0] = 0;
    int xcd = __builtin_amdgcn_s_getreg(63508) & 7;  // HW_REG_XCC_ID
    int rank = atomicAdd(&xcd_cnt[xcd], 1);
    role[0] = xcd; role[1] = rank;
  }
  __syncthreads();
  const int xcd = role[0], rank = role[1];
  if (rank >= GH * 4 + 4) return;           // truly spare
  const bool is_y = (rank >= GH * 4);
  const int bg = xcd * 4 + (is_y ? (rank - GH * 4) : rank / GH);
  const int j  = is_y ? 0 : rank % GH;

  const int lane = tid & 63, w = tid >> 6;
  const int l15 = lane & 15, l4 = lane >> 4;
  const float b2v = (l15 < 5) ? b2[l15] : 0.f;

  // ---------------- y-projection blocks (ranks 20-23) ----------------
  if (is_y) {
    if (w >= 2) return;   // 2 waves: rows w*16..w*16+15
    bf16x8 up[10];
#pragma unroll
    for (int kk = 0; kk < 10; ++kk)
      up[kk] = *(const bf16x8*)(Up + ((kk * 4 + l4) * 16 + l15) * 8);
    // wait for all 5 slice blocks of this bg to clear their flag words
    {
      int it = 0;
      while (__hip_atomic_load(ready + bg * FSTR, __ATOMIC_RELAXED,
                               __HIP_MEMORY_SCOPE_AGENT) < GH) {
        __builtin_amdgcn_s_sleep(2);
        if (++it > 200000) break;
      }
    }
    for (int t = 0; t < TT; ++t) {
      poll20(flags + (t * GB + bg) * FSTR);   // wave-wide; inv leaves L1 clean
      const unsigned short* ar =
          hbuf + (t % NSLOT) * (BATCH * KH) + (bg * BS + w * 16 + l15) * KH + l4 * 8;
      f32x4 ay = {0.f, 0.f, 0.f, 0.f};
#pragma unroll
      for (int kk = 0; kk < 10; ++kk) {
        bf16x8 a = *(const bf16x8*)(ar + kk * 32);
        ay = __builtin_amdgcn_mfma_f32_16x16x32_bf16(a, up[kk], ay, 0, 0, 0);
      }
      if (l15 < 5)
#pragma unroll
        for (int q = 0; q < 4; ++q)
          out[((bg * BS + w * 16 + l4 * 4 + q) * TT + t) * 5 + l15] = ay[q] + b2v;
    }
    return;
  }

  // ---------------- LSTM slice blocks (ranks 0-19) ----------------
  // clear OUR flag words (plain stores -> local L2, overwrite any stale line)
  {
    for (int tt = lane; tt < TT; tt += 64)
      ((volatile int*)(flags + (tt * GB + bg) * FSTR))[j * 4 + w] = 0;
    asm volatile("s_waitcnt vmcnt(0)" ::: "memory");
    __syncthreads();
    if (tid == 0)
      __hip_atomic_fetch_add(ready + bg * FSTR, 1, __ATOMIC_RELAXED,
                             __HIP_MEMORY_SCOPE_AGENT);
    int it = 0;
    while (__hip_atomic_load(ready + bg * FSTR, __ATOMIC_RELAXED,
                             __HIP_MEMORY_SCOPE_AGENT) < GH) {
      __builtin_amdgcn_s_sleep(2);
      if (++it > 200000) break;
    }
  }

  if (tid < BS) {
#pragma unroll
    for (int bq = 0; bq < 2; ++bq)
      for (int e = 150; e < XST; ++e) x_lds[bq][tid * XST + e] = 0;
  }

  const int colb = j * 256 + w * 16 + l15;

  bf16x8 bh[10][4], bx[5][4];
#pragma unroll
  for (int kk = 0; kk < 10; ++kk)
#pragma unroll
    for (int g = 0; g < 4; ++g)
      bh[kk][g] = *(const bf16x8*)(Wp + ((kk * 4 + l4) * NCOL + colb + g * 64) * 8);
#pragma unroll
  for (int kk = 0; kk < 5; ++kk)
#pragma unroll
    for (int g = 0; g < 4; ++g)
      bx[kk][g] = *(const bf16x8*)(Wxp + ((kk * 4 + l4) * NCOL + colb + g * 64) * 8);

  float bias[4];
#pragma unroll
  for (int g = 0; g < 4; ++g) bias[g] = bp[colb + g * 64];

  // gather geometry for tid<192
  int xrow = 0, koff = 0, nf2 = 0, f = 0;
  const bool gth = (tid < 192);
  if (gth) {
    xrow = tid / 6; int half = tid % 6; f = half >> 1; int hh = half & 1;
    nf2 = hh ? 12 : 13;
    koff = f * 50 + (hh ? 26 : 0);
  }
  const long idbase = (long)(bg * BS + xrow) * TT * 3 + f;
  const int  eoff   = (koff - f * 50);

  if (gth) {
    int id0 = ids[idbase + 0 * 3];
    const float* src = embed + (long)id0 * 50 + eoff;
    unsigned short* dst = &x_lds[0][xrow * XST + koff];
#pragma unroll
    for (int e = 0; e < 13; ++e)
      if (e < nf2) {
        float2 v = *(const float2*)(src + 2 * e);
        *(unsigned*)(dst + 2 * e) = (unsigned)f2b(v.x) | ((unsigned)f2b(v.y) << 16);
      }
  }
  __syncthreads();

  f32x4 acc[4][2];
  float cst[2][4];
#pragma unroll
  for (int g = 0; g < 4; ++g)
#pragma unroll
    for (int mt = 0; mt < 2; ++mt) acc[g][mt] = {0.f, 0.f, 0.f, 0.f};
#pragma unroll
  for (int mt = 0; mt < 2; ++mt)
#pragma unroll
    for (int r = 0; r < 4; ++r) cst[mt][r] = 0.f;

  // GEMM1(0)
  {
    const unsigned short* xb = &x_lds[0][l15 * XST + l4 * 8];
#pragma unroll
    for (int kk = 0; kk < 5; ++kk) {
      bf16x8 a0 = *(const bf16x8*)(xb + kk * 32);
      bf16x8 a1 = *(const bf16x8*)(xb + 16 * XST + kk * 32);
#pragma unroll
      for (int g = 0; g < 4; ++g) {
        mfma_bA(a0, bx[kk][g], acc[g][0]);
        mfma_bA(a1, bx[kk][g], acc[g][1]);
      }
    }
  }

  float2 xv[13];
  int idv = 0;
  if (gth) {
    int id1 = ids[idbase + 1 * 3];
    const float* src = embed + (long)id1 * 50 + eoff;
#pragma unroll
    for (int e = 0; e < 13; ++e)
      if (e < nf2) xv[e] = *(const float2*)(src + 2 * e);
    idv = ids[idbase + 2 * 3];
  }

  bf16x8 va0[10], va1[10];

  for (int t = 0; t < TT; ++t) {
    if (t > 0) {
      // whole-wave L2-local poll: detection leaves L1 invalidated
      poll20(flags + ((t - 1) * GB + bg) * FSTR);

      const unsigned short* ar =
          hbuf + ((t - 1) % NSLOT) * (BATCH * KH) + (bg * BS + l15) * KH + l4 * 8;
#pragma unroll
      for (int kk = 0; kk < 10; ++kk) {
        va0[kk] = *(const bf16x8*)(ar + kk * 32);
        va1[kk] = *(const bf16x8*)(ar + 16 * KH + kk * 32);
      }
#pragma unroll
      for (int kk = 0; kk < 10; ++kk) {
#pragma unroll
        for (int g = 0; g < 4; ++g) {
          mfma_bA(va0[kk], bh[kk][g], acc[g][0]);
          mfma_bA(va1[kk], bh[kk][g], acc[g][1]);
        }
      }
    }

    // gates + state update; h(t) packed 8B plain stores -> local L2
    unsigned short* hdst = hbuf + (t % NSLOT) * (BATCH * KH);
#pragma unroll
    for (int mt = 0; mt < 2; ++mt) {
#pragma unroll
      for (int r = 0; r < 4; ++r) {
        float zi = acc[0][mt][r] + bias[0];
        float zf = acc[1][mt][r] + bias[1];
        float zg = acc[2][mt][r] + bias[2];
        float zo = acc[3][mt][r] + bias[3];
        float gi = sigm(zi), gf = sigm(zf), go = sigm(zo), gg = tanhf_(zg);
        float c = gf * cst[mt][r] + gi * gg;
        cst[mt][r] = c;
        float h = go * tanhf_(c);
        unsigned v = f2b(h);
        unsigned p1 = v | ((unsigned)__shfl_xor((int)v, 1) << 16);
        unsigned long long p2 = (unsigned long long)p1 |
            ((unsigned long long)(unsigned)__shfl_xor((int)p1, 2) << 32);
        if ((l15 & 3) == 0) {
          int row = bg * BS + mt * 16 + l4 * 4 + r;
          *(unsigned long long*)(hdst + row * KH + j * SL + w * 16 + l15) = p2;
        }
      }
      acc[0][mt] = {0.f, 0.f, 0.f, 0.f};
      acc[1][mt] = {0.f, 0.f, 0.f, 0.f};
      acc[2][mt] = {0.f, 0.f, 0.f, 0.f};
      acc[3][mt] = {0.f, 0.f, 0.f, 0.f};
    }

    // per-wave release: h stores L2-acked, then plain flag-word store (L2)
    asm volatile("s_waitcnt vmcnt(0)" ::: "memory");
    if (lane == 0)
      ((volatile int*)(flags + (t * GB + bg) * FSTR))[j * 4 + w] = -1;

    // tail: pack x(t+1); GEMM1(t+1); refill pipeline
    if (t + 1 < TT) {
      if (gth) {
        unsigned short* dst = &x_lds[(t + 1) & 1][xrow * XST + koff];
#pragma unroll
        for (int e = 0; e < 13; ++e)
          if (e < nf2)
            *(unsigned*)(dst + 2 * e) = (unsigned)f2b(xv[e].x) | ((unsigned)f2b(xv[e].y) << 16);
      }
      __syncthreads();
      const unsigned short* xb = &x_lds[(t + 1) & 1][l15 * XST + l4 * 8];
#pragma unroll
      for (int kk = 0; kk < 5; ++kk) {
        bf16x8 a0 = *(const bf16x8*)(xb + kk * 32);
        bf16x8 a1 = *(const bf16x8*)(xb + 16 * XST + kk * 32);
#pragma unroll
        for (int g = 0; g < 4; ++g) {
          mfma_bA(a0, bx[kk][g], acc[g][0]);
          mfma_bA(a1, bx[kk][g], acc[g][1]);
        }
      }
      if (gth && t + 2 < TT) {
        const float* src = embed + (long)idv * 50 + eoff;
#pragma unroll
        for (int e = 0; e < 13; ++e)
          if (e < nf2) xv[e] = *(const float2*)(src + 2 * e);
        if (t + 3 < TT) idv = ids[idbase + (long)(t + 3) * 3];
      }
    }
  }
}

extern "C" void kernel_launch(void* const* d_in, const int* in_sizes, int n_in,
                              void* d_out, int out_size, void* d_ws, size_t ws_size,
                              hipStream_t stream) {
  const int*   ids   = (const int*)d_in[0];
  const float* embed = (const float*)d_in[1];
  const float* Wx    = (const float*)d_in[2];
  const float* Wh    = (const float*)d_in[3];
  const float* b     = (const float*)d_in[4];
  const float* U     = (const float*)d_in[5];
  const float* b2    = (const float*)d_in[6];
  float* out = (float*)d_out;

  char* ws = (char*)d_ws;
  size_t off = 0;
  unsigned short* Wp   = (unsigned short*)(ws + off); off += (size_t)KH * NCOL * 2;          //   819,200
  unsigned short* Wxp  = (unsigned short*)(ws + off); off += (size_t)KX * NCOL * 2;          //   409,600
  float*          bp   = (float*)(ws + off);          off += (size_t)NCOL * 4;               //     5,120
  unsigned short* Up   = (unsigned short*)(ws + off); off += (size_t)KH * 16 * 2;            //    10,240
  unsigned short* hbuf = (unsigned short*)(ws + off); off += (size_t)NSLOT * BATCH * KH * 2; // 5,242,880
  int*            flags= (int*)(ws + off);            off += (size_t)TT * GB * FSTR * 4;     //   491,520
  int*            ready= (int*)(ws + off);            off += (size_t)GB * FSTR * 4;          //     4,096
  int*            xcd_cnt = (int*)(ws + off);         off += 8 * 4;                          //        32
  if (ws_size < off) return;  // ~7.0 MB required

  k_init<<<(GB * FSTR + 255) / 256, 256, 0, stream>>>(ready, xcd_cnt);
  k_reorder_wh<<<(KH * NCOL + 255) / 256, 256, 0, stream>>>(Wh, Wp);
  k_reorder_wx<<<(KX * NCOL + 255) / 256, 256, 0, stream>>>(Wx, Wxp);
  k_reorder_b<<<(NCOL + 255) / 256, 256, 0, stream>>>(b, bp);
  k_reorder_u<<<(KH * 16 + 255) / 256, 256, 0, stream>>>(U, Up);

  k_lstm<<<dim3(NB), dim3(256), 0, stream>>>(ids, embed, Wp, Wxp, bp, Up,
                                             hbuf, flags, ready, xcd_cnt, b2, out);
}

// Round 17
// 671.958 us; speedup vs baseline: 1.3456x; 1.3456x over previous
//
#include <hip/hip_runtime.h>

// LSTM: VOCAB=50000, EMBED=50, NFEAT=3, T=120, HIDDEN=300, NCLASS=5, BATCH=1024
// FINAL (= R13, proven 672us, correct + replay-stable):
//  - 256 blocks, 83KB LDS -> 1 block/CU; XCC_ID ranking puts all 5 hidden
//    slices of a batch-group on ONE XCD (shared L2).
//  - h exchange: plain write-through 8B stores -> local L2; consumers
//    buffer_inv (L1) + plain cached loads (L2 hits). FETCH ~45MB total.
//  - sync: compiler-generated AGENT-relaxed fetch_add (release, per wave)
//    + AGENT-relaxed poll (lane0/wave). The ONLY protocol proven both fast
//    and sound on this HW across 16 rounds.
//  - weights AGPR-pinned via "a"-constrained inline-asm MFMA (frees arch
//    VGPRs; bh+bx resident across all 120 steps).
//  - 3-deep x pipeline (ids t+3 -> embed t+2 -> pack t+1) off the chain;
//    y-projection via MFMA from register-resident A-frags, post-release.

#define BATCH 1024
#define TT    120
#define HID   300
#define KX    160
#define KH    320   // 5 slices * 64
#define SL    64
#define HSL   60
#define NCOL  1280  // 5 slices * 256 packed gate columns
#define GH    5
#define GB    32
#define BS    32
#define XST   168   // x_lds row stride in shorts
#define FSTR  32    // flag stride in ints (128B)
#define NSLOT 3
#define NB    256
#define NREL  (GH * 4)   // releases per (t,bg): 5 slices x 4 waves

typedef __attribute__((ext_vector_type(8))) short bf16x8;
typedef __attribute__((ext_vector_type(4))) float f32x4;

__device__ __forceinline__ unsigned short f2b(float f) {
  union { float f; unsigned u; } v; v.f = f;
  unsigned r = v.u + 0x7fffu + ((v.u >> 16) & 1u);
  return (unsigned short)(r >> 16);
}
__device__ __forceinline__ float sigm(float x) {
  return __builtin_amdgcn_rcpf(1.f + __expf(-x));
}
__device__ __forceinline__ float tanhf_(float x) {
  return 2.f * __builtin_amdgcn_rcpf(1.f + __expf(-2.f * x)) - 1.f;
}
// MFMA with B operand pinned to AGPRs ("a" constraint): weights stay resident
// in the unified file's acc half, off the arch-VGPR budget and off L2.
__device__ __forceinline__ void mfma_bA(bf16x8 a, const bf16x8& b, f32x4& c) {
  asm("v_mfma_f32_16x16x32_bf16 %0, %1, %2, %0" : "+v"(c) : "v"(a), "a"(b));
}

__global__ void k_reorder_wh(const float* __restrict__ W, unsigned short* __restrict__ Wp) {
  int tid = blockIdx.x * 256 + threadIdx.x;
  if (tid >= KH * NCOL) return;
  int c = tid % NCOL, k = tid / NCOL;
  int js = k >> 6, v0 = k & 63;
  int j = c >> 8, r = c & 255, g = r >> 6, u0 = r & 63;
  float val = 0.f;
  if (v0 < HSL && u0 < HSL) val = W[(js * HSL + v0) * 1200 + g * 300 + j * HSL + u0];
  Wp[((k >> 3) * NCOL + c) * 8 + (k & 7)] = f2b(val);
}

__global__ void k_reorder_wx(const float* __restrict__ W, unsigned short* __restrict__ Wp) {
  int tid = blockIdx.x * 256 + threadIdx.x;
  if (tid >= KX * NCOL) return;
  int c = tid % NCOL, k = tid / NCOL;
  int j = c >> 8, r = c & 255, g = r >> 6, u0 = r & 63;
  float val = 0.f;
  if (k < 150 && u0 < HSL) val = W[k * 1200 + g * 300 + j * HSL + u0];
  Wp[((k >> 3) * NCOL + c) * 8 + (k & 7)] = f2b(val);
}

__global__ void k_reorder_b(const float* __restrict__ b, float* __restrict__ bp) {
  int c = blockIdx.x * 256 + threadIdx.x;
  if (c >= NCOL) return;
  int j = c >> 8, r = c & 255, g = r >> 6, u0 = r & 63;
  bp[c] = (u0 < HSL) ? b[g * 300 + j * HSL + u0] : 0.f;
}

__global__ void k_reorder_u(const float* __restrict__ U, unsigned short* __restrict__ Up) {
  int tid = blockIdx.x * 256 + threadIdx.x;
  if (tid >= KH * 16) return;
  int n = tid % 16, k = tid / 16;
  int js = k >> 6, v0 = k & 63;
  float v = (v0 < HSL && n < 5) ? U[(js * HSL + v0) * 5 + n] : 0.f;
  Up[((k >> 3) * 16 + n) * 8 + (k & 7)] = f2b(v);
}

// atomic-store init for flags/xcd_cnt (no dirty-line hazard)
__global__ void k_init(int* __restrict__ flags, int n, int* __restrict__ xcd_cnt) {
  int i = blockIdx.x * 256 + threadIdx.x;
  if (i < n)
    __hip_atomic_store(flags + i, 0, __ATOMIC_RELAXED, __HIP_MEMORY_SCOPE_AGENT);
  if (i < 8)
    __hip_atomic_store(xcd_cnt + i, 0, __ATOMIC_RELAXED, __HIP_MEMORY_SCOPE_AGENT);
}

__launch_bounds__(256, 1)
__global__ void k_lstm(const int* __restrict__ ids, const float* __restrict__ embed,
                       const unsigned short* __restrict__ Wp,
                       const unsigned short* __restrict__ Wxp,
                       const float* __restrict__ bp,
                       const unsigned short* __restrict__ Up,
                       unsigned short* __restrict__ hbuf,   // [3][1024][320] bf16
                       int* __restrict__ flags,             // [120][32] @128B counters
                       int* __restrict__ xcd_cnt,           // [8]
                       const float* __restrict__ b2,
                       float* __restrict__ out) {
  __shared__ __align__(16) unsigned short x_lds[2][BS * XST];
  __shared__ char lds_pad[61440];   // force 1 block/CU (total LDS > 80KB)
  __shared__ int role[2];

  const int tid = threadIdx.x;
  if (tid == 0) {
    ((volatile char*)lds_pad)[0] = 0;
    int xcd = __builtin_amdgcn_s_getreg(63508) & 7;  // HW_REG_XCC_ID
    int rank = atomicAdd(&xcd_cnt[xcd], 1);
    role[0] = xcd; role[1] = rank;
  }
  __syncthreads();
  const int xcd = role[0], rank = role[1];
  if (rank >= GH * 4) return;               // spare block
  const int bg = xcd * 4 + rank / GH;
  const int j  = rank % GH;

  const int lane = tid & 63, w = tid >> 6;
  const int l15 = lane & 15, l4 = lane >> 4;

  if (tid < BS) {
#pragma unroll
    for (int bq = 0; bq < 2; ++bq)
      for (int e = 150; e < XST; ++e) x_lds[bq][tid * XST + e] = 0;
  }

  const int colb = j * 256 + w * 16 + l15;

  // persistent B fragments -> AGPRs via "a"-constrained MFMA uses
  bf16x8 bh[10][4], bx[5][4];
#pragma unroll
  for (int kk = 0; kk < 10; ++kk)
#pragma unroll
    for (int g = 0; g < 4; ++g)
      bh[kk][g] = *(const bf16x8*)(Wp + ((kk * 4 + l4) * NCOL + colb + g * 64) * 8);
#pragma unroll
  for (int kk = 0; kk < 5; ++kk)
#pragma unroll
    for (int g = 0; g < 4; ++g)
      bx[kk][g] = *(const bf16x8*)(Wxp + ((kk * 4 + l4) * NCOL + colb + g * 64) * 8);

  float bias[4];
#pragma unroll
  for (int g = 0; g < 4; ++g) bias[g] = bp[colb + g * 64];
  const float b2v = (l15 < 5) ? b2[l15] : 0.f;

  // gather geometry for tid<192
  int xrow = 0, koff = 0, nf2 = 0, f = 0;
  const bool gth = (tid < 192);
  if (gth) {
    xrow = tid / 6; int half = tid % 6; f = half >> 1; int hh = half & 1;
    nf2 = hh ? 12 : 13;
    koff = f * 50 + (hh ? 26 : 0);
  }
  const long idbase = (long)(bg * BS + xrow) * TT * 3 + f;
  const int  eoff   = (koff - f * 50);

  // prologue: x(0) gather+pack
  if (gth) {
    int id0 = ids[idbase + 0 * 3];
    const float* src = embed + (long)id0 * 50 + eoff;
    unsigned short* dst = &x_lds[0][xrow * XST + koff];
#pragma unroll
    for (int e = 0; e < 13; ++e)
      if (e < nf2) {
        float2 v = *(const float2*)(src + 2 * e);
        *(unsigned*)(dst + 2 * e) = (unsigned)f2b(v.x) | ((unsigned)f2b(v.y) << 16);
      }
  }
  __syncthreads();

  f32x4 acc[4][2];
  float cst[2][4];
#pragma unroll
  for (int g = 0; g < 4; ++g)
#pragma unroll
    for (int mt = 0; mt < 2; ++mt) acc[g][mt] = {0.f, 0.f, 0.f, 0.f};
#pragma unroll
  for (int mt = 0; mt < 2; ++mt)
#pragma unroll
    for (int r = 0; r < 4; ++r) cst[mt][r] = 0.f;

  // GEMM1(0)
  {
    const unsigned short* xb = &x_lds[0][l15 * XST + l4 * 8];
#pragma unroll
    for (int kk = 0; kk < 5; ++kk) {
      bf16x8 a0 = *(const bf16x8*)(xb + kk * 32);
      bf16x8 a1 = *(const bf16x8*)(xb + 16 * XST + kk * 32);
#pragma unroll
      for (int g = 0; g < 4; ++g) {
        mfma_bA(a0, bx[kk][g], acc[g][0]);
        mfma_bA(a1, bx[kk][g], acc[g][1]);
      }
    }
  }

  // pipeline regs: xv = embed(t+1) floats; idv = ids(t+2)
  float2 xv[13];
  int idv = 0;
  if (gth) {
    int id1 = ids[idbase + 1 * 3];
    const float* src = embed + (long)id1 * 50 + eoff;
#pragma unroll
    for (int e = 0; e < 13; ++e)
      if (e < nf2) xv[e] = *(const float2*)(src + 2 * e);
    idv = ids[idbase + 2 * 3];
  }

  bf16x8 va0[10], va1[10];

  for (int t = 0; t < TT; ++t) {
    if (t > 0) {
      // per-wave gate: lane 0 polls (R8-proven relaxed-AGENT load), wave joins
      if (lane == 0) {
        const int* fp = flags + ((t - 1) * GB + bg) * FSTR;
        int it = 0;
        while (__hip_atomic_load(fp, __ATOMIC_RELAXED, __HIP_MEMORY_SCOPE_AGENT) < NREL) {
          if (++it > 500000) break;  // bail -> wrong answer, not a hang
        }
      }
      // per-wave: drop stale L1, then read partners' h from XCD L2 (R8-proven)
      asm volatile("buffer_inv\n\ts_waitcnt vmcnt(0)" ::: "memory");

      const unsigned short* ar =
          hbuf + ((t - 1) % NSLOT) * (BATCH * KH) + (bg * BS + l15) * KH + l4 * 8;
#pragma unroll
      for (int kk = 0; kk < 10; ++kk) {
        va0[kk] = *(const bf16x8*)(ar + kk * 32);
        va1[kk] = *(const bf16x8*)(ar + 16 * KH + kk * 32);
      }
#pragma unroll
      for (int kk = 0; kk < 10; ++kk) {
#pragma unroll
        for (int g = 0; g < 4; ++g) {
          mfma_bA(va0[kk], bh[kk][g], acc[g][0]);
          mfma_bA(va1[kk], bh[kk][g], acc[g][1]);
        }
      }
    }

    // gates + state update; h(t) packed 8B plain write-through stores -> local L2
    unsigned short* hdst = hbuf + (t % NSLOT) * (BATCH * KH);
#pragma unroll
    for (int mt = 0; mt < 2; ++mt) {
#pragma unroll
      for (int r = 0; r < 4; ++r) {
        float zi = acc[0][mt][r] + bias[0];
        float zf = acc[1][mt][r] + bias[1];
        float zg = acc[2][mt][r] + bias[2];
        float zo = acc[3][mt][r] + bias[3];
        float gi = sigm(zi), gf = sigm(zf), go = sigm(zo), gg = tanhf_(zg);
        float c = gf * cst[mt][r] + gi * gg;
        cst[mt][r] = c;
        float h = go * tanhf_(c);
        unsigned v = f2b(h);
        unsigned p1 = v | ((unsigned)__shfl_xor((int)v, 1) << 16);
        unsigned long long p2 = (unsigned long long)p1 |
            ((unsigned long long)(unsigned)__shfl_xor((int)p1, 2) << 32);
        if ((l15 & 3) == 0) {
          int row = bg * BS + mt * 16 + l4 * 4 + r;
          *(unsigned long long*)(hdst + row * KH + j * SL + w * 16 + l15) = p2;
        }
      }
      acc[0][mt] = {0.f, 0.f, 0.f, 0.f};
      acc[1][mt] = {0.f, 0.f, 0.f, 0.f};
      acc[2][mt] = {0.f, 0.f, 0.f, 0.f};
      acc[3][mt] = {0.f, 0.f, 0.f, 0.f};
    }

    // per-wave release: own stores L2-acked, then lane0 fetch_add (R8-proven op)
    asm volatile("s_waitcnt vmcnt(0)" ::: "memory");
    if (lane == 0)
      __hip_atomic_fetch_add(flags + (t * GB + bg) * FSTR, 1, __ATOMIC_RELAXED,
                             __HIP_MEMORY_SCOPE_AGENT);

    // y(t-1) duty from register A-frags (waves 2/3; post-release, off chain)
    if (t > 0 && j == (t - 1) % GH) {
      if (w == 2) {
        f32x4 ay = {0.f, 0.f, 0.f, 0.f};
#pragma unroll
        for (int kk = 0; kk < 10; ++kk) {
          bf16x8 u = *(const bf16x8*)(Up + ((kk * 4 + l4) * 16 + l15) * 8);
          ay = __builtin_amdgcn_mfma_f32_16x16x32_bf16(va0[kk], u, ay, 0, 0, 0);
        }
        if (l15 < 5)
#pragma unroll
          for (int q = 0; q < 4; ++q)
            out[((bg * BS + l4 * 4 + q) * TT + (t - 1)) * 5 + l15] = ay[q] + b2v;
      } else if (w == 3) {
        f32x4 ay = {0.f, 0.f, 0.f, 0.f};
#pragma unroll
        for (int kk = 0; kk < 10; ++kk) {
          bf16x8 u = *(const bf16x8*)(Up + ((kk * 4 + l4) * 16 + l15) * 8);
          ay = __builtin_amdgcn_mfma_f32_16x16x32_bf16(va1[kk], u, ay, 0, 0, 0);
        }
        if (l15 < 5)
#pragma unroll
          for (int q = 0; q < 4; ++q)
            out[((bg * BS + 16 + l4 * 4 + q) * TT + (t - 1)) * 5 + l15] = ay[q] + b2v;
      }
    }

    // tail: pack x(t+1); GEMM1(t+1); refill pipeline (t+2 embed, t+3 ids)
    if (t + 1 < TT) {
      if (gth) {
        unsigned short* dst = &x_lds[(t + 1) & 1][xrow * XST + koff];
#pragma unroll
        for (int e = 0; e < 13; ++e)
          if (e < nf2)
            *(unsigned*)(dst + 2 * e) = (unsigned)f2b(xv[e].x) | ((unsigned)f2b(xv[e].y) << 16);
      }
      __syncthreads();
      const unsigned short* xb = &x_lds[(t + 1) & 1][l15 * XST + l4 * 8];
#pragma unroll
      for (int kk = 0; kk < 5; ++kk) {
        bf16x8 a0 = *(const bf16x8*)(xb + kk * 32);
        bf16x8 a1 = *(const bf16x8*)(xb + 16 * XST + kk * 32);
#pragma unroll
        for (int g = 0; g < 4; ++g) {
          mfma_bA(a0, bx[kk][g], acc[g][0]);
          mfma_bA(a1, bx[kk][g], acc[g][1]);
        }
      }
      if (gth && t + 2 < TT) {
        const float* src = embed + (long)idv * 50 + eoff;
#pragma unroll
        for (int e = 0; e < 13; ++e)
          if (e < nf2) xv[e] = *(const float2*)(src + 2 * e);
        if (t + 3 < TT) idv = ids[idbase + (long)(t + 3) * 3];
      }
    }
  }

  // epilogue: y(119) by slice 4
  if (j == (TT - 1) % GH) {
    if (lane == 0) {
      const int* fp = flags + ((TT - 1) * GB + bg) * FSTR;
      int it = 0;
      while (__hip_atomic_load(fp, __ATOMIC_RELAXED, __HIP_MEMORY_SCOPE_AGENT) < NREL) {
        if (++it > 500000) break;
      }
    }
    asm volatile("buffer_inv\n\ts_waitcnt vmcnt(0)" ::: "memory");
    const unsigned short* ar =
        hbuf + ((TT - 1) % NSLOT) * (BATCH * KH) + (bg * BS + l15) * KH + l4 * 8;
#pragma unroll
    for (int kk = 0; kk < 10; ++kk) {
      va0[kk] = *(const bf16x8*)(ar + kk * 32);
      va1[kk] = *(const bf16x8*)(ar + 16 * KH + kk * 32);
    }
    if (w == 2) {
      f32x4 ay = {0.f, 0.f, 0.f, 0.f};
#pragma unroll
      for (int kk = 0; kk < 10; ++kk) {
        bf16x8 u = *(const bf16x8*)(Up + ((kk * 4 + l4) * 16 + l15) * 8);
        ay = __builtin_amdgcn_mfma_f32_16x16x32_bf16(va0[kk], u, ay, 0, 0, 0);
      }
      if (l15 < 5)
#pragma unroll
        for (int q = 0; q < 4; ++q)
          out[((bg * BS + l4 * 4 + q) * TT + (TT - 1)) * 5 + l15] = ay[q] + b2v;
    } else if (w == 3) {
      f32x4 ay = {0.f, 0.f, 0.f, 0.f};
#pragma unroll
      for (int kk = 0; kk < 10; ++kk) {
        bf16x8 u = *(const bf16x8*)(Up + ((kk * 4 + l4) * 16 + l15) * 8);
        ay = __builtin_amdgcn_mfma_f32_16x16x32_bf16(va1[kk], u, ay, 0, 0, 0);
      }
      if (l15 < 5)
#pragma unroll
        for (int q = 0; q < 4; ++q)
          out[((bg * BS + 16 + l4 * 4 + q) * TT + (TT - 1)) * 5 + l15] = ay[q] + b2v;
    }
  }
}

extern "C" void kernel_launch(void* const* d_in, const int* in_sizes, int n_in,
                              void* d_out, int out_size, void* d_ws, size_t ws_size,
                              hipStream_t stream) {
  const int*   ids   = (const int*)d_in[0];
  const float* embed = (const float*)d_in[1];
  const float* Wx    = (const float*)d_in[2];
  const float* Wh    = (const float*)d_in[3];
  const float* b     = (const float*)d_in[4];
  const float* U     = (const float*)d_in[5];
  const float* b2    = (const float*)d_in[6];
  float* out = (float*)d_out;

  char* ws = (char*)d_ws;
  size_t off = 0;
  unsigned short* Wp   = (unsigned short*)(ws + off); off += (size_t)KH * NCOL * 2;
  unsigned short* Wxp  = (unsigned short*)(ws + off); off += (size_t)KX * NCOL * 2;
  float*          bp   = (float*)(ws + off);          off += (size_t)NCOL * 4;
  unsigned short* Up   = (unsigned short*)(ws + off); off += (size_t)KH * 16 * 2;
  unsigned short* hbuf = (unsigned short*)(ws + off); off += (size_t)NSLOT * BATCH * KH * 2;
  int*            flags= (int*)(ws + off);            off += (size_t)TT * GB * FSTR * 4;
  int*            xcd_cnt = (int*)(ws + off);         off += 8 * 4;
  if (ws_size < off) return;  // ~3.7 MB required

  k_init<<<(TT * GB * FSTR + 255) / 256, 256, 0, stream>>>(flags, TT * GB * FSTR, xcd_cnt);
  k_reorder_wh<<<(KH * NCOL + 255) / 256, 256, 0, stream>>>(Wh, Wp);
  k_reorder_wx<<<(KX * NCOL + 255) / 256, 256, 0, stream>>>(Wx, Wxp);
  k_reorder_b<<<(NCOL + 255) / 256, 256, 0, stream>>>(b, bp);
  k_reorder_u<<<(KH * 16 + 255) / 256, 256, 0, stream>>>(U, Up);

  k_lstm<<<dim3(NB), dim3(256), 0, stream>>>(ids, embed, Wp, Wxp, bp, Up,
                                             hbuf, flags, xcd_cnt, b2, out);
}

// Round 18
// 671.831 us; speedup vs baseline: 1.3459x; 1.0002x over previous
//
#include <hip/hip_runtime.h>

// LSTM: VOCAB=50000, EMBED=50, NFEAT=3, T=120, HIDDEN=300, NCLASS=5, BATCH=1024
// R18 = R17/R13 (proven 672us) with ONE change: scatter-flag release.
//  - release: each (slice,wave) does a relaxed-AGENT atomic STORE of 1 to its
//    OWN flag word (j*4+w) -> zero same-line RMW serialization at the
//    coherent point (R13 had 20 fetch_adds queuing on one address).
//  - poll: lane-parallel - lanes 0..19 each relaxed-AGENT load their word,
//    __all(v!=0); one wave memory op per iteration, whole-wave uniform loop.
//  - ordering identical to R13: vmcnt-drained h stores (shared XCD L2)
//    strictly precede the L3 flag store; consumer sees flag => h is in L2.
// Everything else byte-identical to R17.

#define BATCH 1024
#define TT    120
#define HID   300
#define KX    160
#define KH    320   // 5 slices * 64
#define SL    64
#define HSL   60
#define NCOL  1280  // 5 slices * 256 packed gate columns
#define GH    5
#define GB    32
#define BS    32
#define XST   168   // x_lds row stride in shorts
#define FSTR  32    // flag stride in ints (128B)
#define NSLOT 3
#define NB    256
#define NREL  (GH * 4)   // flag words per (t,bg): 5 slices x 4 waves

typedef __attribute__((ext_vector_type(8))) short bf16x8;
typedef __attribute__((ext_vector_type(4))) float f32x4;

__device__ __forceinline__ unsigned short f2b(float f) {
  union { float f; unsigned u; } v; v.f = f;
  unsigned r = v.u + 0x7fffu + ((v.u >> 16) & 1u);
  return (unsigned short)(r >> 16);
}
__device__ __forceinline__ float sigm(float x) {
  return __builtin_amdgcn_rcpf(1.f + __expf(-x));
}
__device__ __forceinline__ float tanhf_(float x) {
  return 2.f * __builtin_amdgcn_rcpf(1.f + __expf(-2.f * x)) - 1.f;
}
// MFMA with B operand pinned to AGPRs (R13-proven)
__device__ __forceinline__ void mfma_bA(bf16x8 a, const bf16x8& b, f32x4& c) {
  asm("v_mfma_f32_16x16x32_bf16 %0, %1, %2, %0" : "+v"(c) : "v"(a), "a"(b));
}
// lane-parallel poll: lanes 0..NREL-1 each watch one flag word (all proven ops)
__device__ __forceinline__ void poll_scatter(const int* fp, int lane) {
  int it = 0;
  while (true) {
    int v = 1;
    if (lane < NREL)
      v = __hip_atomic_load(fp + lane, __ATOMIC_RELAXED, __HIP_MEMORY_SCOPE_AGENT);
    if (__all(v != 0)) break;
    if (++it > 500000) break;  // bail -> wrong answer (loud), not a hang
  }
}

__global__ void k_reorder_wh(const float* __restrict__ W, unsigned short* __restrict__ Wp) {
  int tid = blockIdx.x * 256 + threadIdx.x;
  if (tid >= KH * NCOL) return;
  int c = tid % NCOL, k = tid / NCOL;
  int js = k >> 6, v0 = k & 63;
  int j = c >> 8, r = c & 255, g = r >> 6, u0 = r & 63;
  float val = 0.f;
  if (v0 < HSL && u0 < HSL) val = W[(js * HSL + v0) * 1200 + g * 300 + j * HSL + u0];
  Wp[((k >> 3) * NCOL + c) * 8 + (k & 7)] = f2b(val);
}

__global__ void k_reorder_wx(const float* __restrict__ W, unsigned short* __restrict__ Wp) {
  int tid = blockIdx.x * 256 + threadIdx.x;
  if (tid >= KX * NCOL) return;
  int c = tid % NCOL, k = tid / NCOL;
  int j = c >> 8, r = c & 255, g = r >> 6, u0 = r & 63;
  float val = 0.f;
  if (k < 150 && u0 < HSL) val = W[k * 1200 + g * 300 + j * HSL + u0];
  Wp[((k >> 3) * NCOL + c) * 8 + (k & 7)] = f2b(val);
}

__global__ void k_reorder_b(const float* __restrict__ b, float* __restrict__ bp) {
  int c = blockIdx.x * 256 + threadIdx.x;
  if (c >= NCOL) return;
  int j = c >> 8, r = c & 255, g = r >> 6, u0 = r & 63;
  bp[c] = (u0 < HSL) ? b[g * 300 + j * HSL + u0] : 0.f;
}

__global__ void k_reorder_u(const float* __restrict__ U, unsigned short* __restrict__ Up) {
  int tid = blockIdx.x * 256 + threadIdx.x;
  if (tid >= KH * 16) return;
  int n = tid % 16, k = tid / 16;
  int js = k >> 6, v0 = k & 63;
  float v = (v0 < HSL && n < 5) ? U[(js * HSL + v0) * 5 + n] : 0.f;
  Up[((k >> 3) * 16 + n) * 8 + (k & 7)] = f2b(v);
}

// atomic-store init for flags/xcd_cnt (no dirty-line hazard)
__global__ void k_init(int* __restrict__ flags, int n, int* __restrict__ xcd_cnt) {
  int i = blockIdx.x * 256 + threadIdx.x;
  if (i < n)
    __hip_atomic_store(flags + i, 0, __ATOMIC_RELAXED, __HIP_MEMORY_SCOPE_AGENT);
  if (i < 8)
    __hip_atomic_store(xcd_cnt + i, 0, __ATOMIC_RELAXED, __HIP_MEMORY_SCOPE_AGENT);
}

__launch_bounds__(256, 1)
__global__ void k_lstm(const int* __restrict__ ids, const float* __restrict__ embed,
                       const unsigned short* __restrict__ Wp,
                       const unsigned short* __restrict__ Wxp,
                       const float* __restrict__ bp,
                       const unsigned short* __restrict__ Up,
                       unsigned short* __restrict__ hbuf,   // [3][1024][320] bf16
                       int* __restrict__ flags,             // [120][32][32] words
                       int* __restrict__ xcd_cnt,           // [8]
                       const float* __restrict__ b2,
                       float* __restrict__ out) {
  __shared__ __align__(16) unsigned short x_lds[2][BS * XST];
  __shared__ char lds_pad[61440];   // force 1 block/CU (total LDS > 80KB)
  __shared__ int role[2];

  const int tid = threadIdx.x;
  if (tid == 0) {
    ((volatile char*)lds_pad)[0] = 0;
    int xcd = __builtin_amdgcn_s_getreg(63508) & 7;  // HW_REG_XCC_ID
    int rank = atomicAdd(&xcd_cnt[xcd], 1);
    role[0] = xcd; role[1] = rank;
  }
  __syncthreads();
  const int xcd = role[0], rank = role[1];
  if (rank >= GH * 4) return;               // spare block
  const int bg = xcd * 4 + rank / GH;
  const int j  = rank % GH;

  const int lane = tid & 63, w = tid >> 6;
  const int l15 = lane & 15, l4 = lane >> 4;

  if (tid < BS) {
#pragma unroll
    for (int bq = 0; bq < 2; ++bq)
      for (int e = 150; e < XST; ++e) x_lds[bq][tid * XST + e] = 0;
  }

  const int colb = j * 256 + w * 16 + l15;

  // persistent B fragments -> AGPRs via "a"-constrained MFMA uses
  bf16x8 bh[10][4], bx[5][4];
#pragma unroll
  for (int kk = 0; kk < 10; ++kk)
#pragma unroll
    for (int g = 0; g < 4; ++g)
      bh[kk][g] = *(const bf16x8*)(Wp + ((kk * 4 + l4) * NCOL + colb + g * 64) * 8);
#pragma unroll
  for (int kk = 0; kk < 5; ++kk)
#pragma unroll
    for (int g = 0; g < 4; ++g)
      bx[kk][g] = *(const bf16x8*)(Wxp + ((kk * 4 + l4) * NCOL + colb + g * 64) * 8);

  float bias[4];
#pragma unroll
  for (int g = 0; g < 4; ++g) bias[g] = bp[colb + g * 64];
  const float b2v = (l15 < 5) ? b2[l15] : 0.f;

  // gather geometry for tid<192
  int xrow = 0, koff = 0, nf2 = 0, f = 0;
  const bool gth = (tid < 192);
  if (gth) {
    xrow = tid / 6; int half = tid % 6; f = half >> 1; int hh = half & 1;
    nf2 = hh ? 12 : 13;
    koff = f * 50 + (hh ? 26 : 0);
  }
  const long idbase = (long)(bg * BS + xrow) * TT * 3 + f;
  const int  eoff   = (koff - f * 50);

  // prologue: x(0) gather+pack
  if (gth) {
    int id0 = ids[idbase + 0 * 3];
    const float* src = embed + (long)id0 * 50 + eoff;
    unsigned short* dst = &x_lds[0][xrow * XST + koff];
#pragma unroll
    for (int e = 0; e < 13; ++e)
      if (e < nf2) {
        float2 v = *(const float2*)(src + 2 * e);
        *(unsigned*)(dst + 2 * e) = (unsigned)f2b(v.x) | ((unsigned)f2b(v.y) << 16);
      }
  }
  __syncthreads();

  f32x4 acc[4][2];
  float cst[2][4];
#pragma unroll
  for (int g = 0; g < 4; ++g)
#pragma unroll
    for (int mt = 0; mt < 2; ++mt) acc[g][mt] = {0.f, 0.f, 0.f, 0.f};
#pragma unroll
  for (int mt = 0; mt < 2; ++mt)
#pragma unroll
    for (int r = 0; r < 4; ++r) cst[mt][r] = 0.f;

  // GEMM1(0)
  {
    const unsigned short* xb = &x_lds[0][l15 * XST + l4 * 8];
#pragma unroll
    for (int kk = 0; kk < 5; ++kk) {
      bf16x8 a0 = *(const bf16x8*)(xb + kk * 32);
      bf16x8 a1 = *(const bf16x8*)(xb + 16 * XST + kk * 32);
#pragma unroll
      for (int g = 0; g < 4; ++g) {
        mfma_bA(a0, bx[kk][g], acc[g][0]);
        mfma_bA(a1, bx[kk][g], acc[g][1]);
      }
    }
  }

  // pipeline regs: xv = embed(t+1) floats; idv = ids(t+2)
  float2 xv[13];
  int idv = 0;
  if (gth) {
    int id1 = ids[idbase + 1 * 3];
    const float* src = embed + (long)id1 * 50 + eoff;
#pragma unroll
    for (int e = 0; e < 13; ++e)
      if (e < nf2) xv[e] = *(const float2*)(src + 2 * e);
    idv = ids[idbase + 2 * 3];
  }

  bf16x8 va0[10], va1[10];

  for (int t = 0; t < TT; ++t) {
    if (t > 0) {
      // whole-wave lane-parallel poll of the 20 scatter-flags (proven ops)
      poll_scatter(flags + ((t - 1) * GB + bg) * FSTR, lane);
      // per-wave: drop stale L1, then read partners' h from XCD L2 (R8-proven)
      asm volatile("buffer_inv\n\ts_waitcnt vmcnt(0)" ::: "memory");

      const unsigned short* ar =
          hbuf + ((t - 1) % NSLOT) * (BATCH * KH) + (bg * BS + l15) * KH + l4 * 8;
#pragma unroll
      for (int kk = 0; kk < 10; ++kk) {
        va0[kk] = *(const bf16x8*)(ar + kk * 32);
        va1[kk] = *(const bf16x8*)(ar + 16 * KH + kk * 32);
      }
#pragma unroll
      for (int kk = 0; kk < 10; ++kk) {
#pragma unroll
        for (int g = 0; g < 4; ++g) {
          mfma_bA(va0[kk], bh[kk][g], acc[g][0]);
          mfma_bA(va1[kk], bh[kk][g], acc[g][1]);
        }
      }
    }

    // gates + state update; h(t) packed 8B plain write-through stores -> local L2
    unsigned short* hdst = hbuf + (t % NSLOT) * (BATCH * KH);
#pragma unroll
    for (int mt = 0; mt < 2; ++mt) {
#pragma unroll
      for (int r = 0; r < 4; ++r) {
        float zi = acc[0][mt][r] + bias[0];
        float zf = acc[1][mt][r] + bias[1];
        float zg = acc[2][mt][r] + bias[2];
        float zo = acc[3][mt][r] + bias[3];
        float gi = sigm(zi), gf = sigm(zf), go = sigm(zo), gg = tanhf_(zg);
        float c = gf * cst[mt][r] + gi * gg;
        cst[mt][r] = c;
        float h = go * tanhf_(c);
        unsigned v = f2b(h);
        unsigned p1 = v | ((unsigned)__shfl_xor((int)v, 1) << 16);
        unsigned long long p2 = (unsigned long long)p1 |
            ((unsigned long long)(unsigned)__shfl_xor((int)p1, 2) << 32);
        if ((l15 & 3) == 0) {
          int row = bg * BS + mt * 16 + l4 * 4 + r;
          *(unsigned long long*)(hdst + row * KH + j * SL + w * 16 + l15) = p2;
        }
      }
      acc[0][mt] = {0.f, 0.f, 0.f, 0.f};
      acc[1][mt] = {0.f, 0.f, 0.f, 0.f};
      acc[2][mt] = {0.f, 0.f, 0.f, 0.f};
      acc[3][mt] = {0.f, 0.f, 0.f, 0.f};
    }

    // per-wave release: own stores L2-acked, then atomic STORE to own word
    asm volatile("s_waitcnt vmcnt(0)" ::: "memory");
    if (lane == 0)
      __hip_atomic_store(flags + (t * GB + bg) * FSTR + j * 4 + w, 1,
                         __ATOMIC_RELAXED, __HIP_MEMORY_SCOPE_AGENT);

    // y(t-1) duty from register A-frags (waves 2/3; post-release, off chain)
    if (t > 0 && j == (t - 1) % GH) {
      if (w == 2) {
        f32x4 ay = {0.f, 0.f, 0.f, 0.f};
#pragma unroll
        for (int kk = 0; kk < 10; ++kk) {
          bf16x8 u = *(const bf16x8*)(Up + ((kk * 4 + l4) * 16 + l15) * 8);
          ay = __builtin_amdgcn_mfma_f32_16x16x32_bf16(va0[kk], u, ay, 0, 0, 0);
        }
        if (l15 < 5)
#pragma unroll
          for (int q = 0; q < 4; ++q)
            out[((bg * BS + l4 * 4 + q) * TT + (t - 1)) * 5 + l15] = ay[q] + b2v;
      } else if (w == 3) {
        f32x4 ay = {0.f, 0.f, 0.f, 0.f};
#pragma unroll
        for (int kk = 0; kk < 10; ++kk) {
          bf16x8 u = *(const bf16x8*)(Up + ((kk * 4 + l4) * 16 + l15) * 8);
          ay = __builtin_amdgcn_mfma_f32_16x16x32_bf16(va1[kk], u, ay, 0, 0, 0);
        }
        if (l15 < 5)
#pragma unroll
          for (int q = 0; q < 4; ++q)
            out[((bg * BS + 16 + l4 * 4 + q) * TT + (t - 1)) * 5 + l15] = ay[q] + b2v;
      }
    }

    // tail: pack x(t+1); GEMM1(t+1); refill pipeline (t+2 embed, t+3 ids)
    if (t + 1 < TT) {
      if (gth) {
        unsigned short* dst = &x_lds[(t + 1) & 1][xrow * XST + koff];
#pragma unroll
        for (int e = 0; e < 13; ++e)
          if (e < nf2)
            *(unsigned*)(dst + 2 * e) = (unsigned)f2b(xv[e].x) | ((unsigned)f2b(xv[e].y) << 16);
      }
      __syncthreads();
      const unsigned short* xb = &x_lds[(t + 1) & 1][l15 * XST + l4 * 8];
#pragma unroll
      for (int kk = 0; kk < 5; ++kk) {
        bf16x8 a0 = *(const bf16x8*)(xb + kk * 32);
        bf16x8 a1 = *(const bf16x8*)(xb + 16 * XST + kk * 32);
#pragma unroll
        for (int g = 0; g < 4; ++g) {
          mfma_bA(a0, bx[kk][g], acc[g][0]);
          mfma_bA(a1, bx[kk][g], acc[g][1]);
        }
      }
      if (gth && t + 2 < TT) {
        const float* src = embed + (long)idv * 50 + eoff;
#pragma unroll
        for (int e = 0; e < 13; ++e)
          if (e < nf2) xv[e] = *(const float2*)(src + 2 * e);
        if (t + 3 < TT) idv = ids[idbase + (long)(t + 3) * 3];
      }
    }
  }

  // epilogue: y(119) by slice 4
  if (j == (TT - 1) % GH) {
    poll_scatter(flags + ((TT - 1) * GB + bg) * FSTR, lane);
    asm volatile("buffer_inv\n\ts_waitcnt vmcnt(0)" ::: "memory");
    const unsigned short* ar =
        hbuf + ((TT - 1) % NSLOT) * (BATCH * KH) + (bg * BS + l15) * KH + l4 * 8;
#pragma unroll
    for (int kk = 0; kk < 10; ++kk) {
      va0[kk] = *(const bf16x8*)(ar + kk * 32);
      va1[kk] = *(const bf16x8*)(ar + 16 * KH + kk * 32);
    }
    if (w == 2) {
      f32x4 ay = {0.f, 0.f, 0.f, 0.f};
#pragma unroll
      for (int kk = 0; kk < 10; ++kk) {
        bf16x8 u = *(const bf16x8*)(Up + ((kk * 4 + l4) * 16 + l15) * 8);
        ay = __builtin_amdgcn_mfma_f32_16x16x32_bf16(va0[kk], u, ay, 0, 0, 0);
      }
      if (l15 < 5)
#pragma unroll
        for (int q = 0; q < 4; ++q)
          out[((bg * BS + l4 * 4 + q) * TT + (TT - 1)) * 5 + l15] = ay[q] + b2v;
    } else if (w == 3) {
      f32x4 ay = {0.f, 0.f, 0.f, 0.f};
#pragma unroll
      for (int kk = 0; kk < 10; ++kk) {
        bf16x8 u = *(const bf16x8*)(Up + ((kk * 4 + l4) * 16 + l15) * 8);
        ay = __builtin_amdgcn_mfma_f32_16x16x32_bf16(va1[kk], u, ay, 0, 0, 0);
      }
      if (l15 < 5)
#pragma unroll
        for (int q = 0; q < 4; ++q)
          out[((bg * BS + 16 + l4 * 4 + q) * TT + (TT - 1)) * 5 + l15] = ay[q] + b2v;
    }
  }
}

extern "C" void kernel_launch(void* const* d_in, const int* in_sizes, int n_in,
                              void* d_out, int out_size, void* d_ws, size_t ws_size,
                              hipStream_t stream) {
  const int*   ids   = (const int*)d_in[0];
  const float* embed = (const float*)d_in[1];
  const float* Wx    = (const float*)d_in[2];
  const float* Wh    = (const float*)d_in[3];
  const float* b     = (const float*)d_in[4];
  const float* U     = (const float*)d_in[5];
  const float* b2    = (const float*)d_in[6];
  float* out = (float*)d_out;

  char* ws = (char*)d_ws;
  size_t off = 0;
  unsigned short* Wp   = (unsigned short*)(ws + off); off += (size_t)KH * NCOL * 2;
  unsigned short* Wxp  = (unsigned short*)(ws + off); off += (size_t)KX * NCOL * 2;
  float*          bp   = (float*)(ws + off);          off += (size_t)NCOL * 4;
  unsigned short* Up   = (unsigned short*)(ws + off); off += (size_t)KH * 16 * 2;
  unsigned short* hbuf = (unsigned short*)(ws + off); off += (size_t)NSLOT * BATCH * KH * 2;
  int*            flags= (int*)(ws + off);            off += (size_t)TT * GB * FSTR * 4;
  int*            xcd_cnt = (int*)(ws + off);         off += 8 * 4;
  if (ws_size < off) return;  // ~3.7 MB required

  k_init<<<(TT * GB * FSTR + 255) / 256, 256, 0, stream>>>(flags, TT * GB * FSTR, xcd_cnt);
  k_reorder_wh<<<(KH * NCOL + 255) / 256, 256, 0, stream>>>(Wh, Wp);
  k_reorder_wx<<<(KX * NCOL + 255) / 256, 256, 0, stream>>>(Wx, Wxp);
  k_reorder_b<<<(NCOL + 255) / 256, 256, 0, stream>>>(b, bp);
  k_reorder_u<<<(KH * 16 + 255) / 256, 256, 0, stream>>>(U, Up);

  k_lstm<<<dim3(NB), dim3(256), 0, stream>>>(ids, embed, Wp, Wxp, bp, Up,
                                             hbuf, flags, xcd_cnt, b2, out);
}